// Round 8
// baseline (2416.771 us; speedup 1.0000x reference)
//
#include <hip/hip_runtime.h>

#define D_DIM 1024
#define B_ROWS 65536

typedef unsigned short u16;
typedef __attribute__((ext_vector_type(8))) __bf16 bf16x8;
typedef __attribute__((ext_vector_type(4))) float f32x4;
typedef __attribute__((ext_vector_type(8))) unsigned short u16x8;

__device__ __forceinline__ u16 f2bf(float f) {
  union { float fv; unsigned int i; } v; v.fv = f;
  return (u16)((v.i + 0x7FFFu + ((v.i >> 16) & 1u)) >> 16);
}
__device__ __forceinline__ float bf2f(u16 u) {
  union { unsigned int i; float f; } v; v.i = ((unsigned int)u) << 16; return v.f;
}

// ---------------- GEMM: C = A(bf16) @ W(bf16)^T (+bias) (+R) ----------------
// m201-style 8-phase 256x256 template, reg-staged:
//   BK=64, 8 waves (2M x 4N), per-wave C = 128x64 (acc[8][4]).
//   LDS = 2 K-tile bufs x (A 32KB + B 32KB) = 128 KB.
//   Phase p: ds_write half staged 4 phases ago (counted vmcnt, ~1000cy aging)
//            -> issue 2 global loads (tile t+2/t+3) -> snake quadrant frag
//            reads -> setprio(1) 16 MFMA setprio(0) -> lgkmcnt(0) -> s_barrier.
//   Phases 0-3: read buf0, write buf1. Phases 4-7: read buf1, write buf0.
//   XOR swizzle: phys_granule = g ^ (row&7) on 128B rows (R5/R6: 0 conflicts).
#define BM 256
#define BN 256
#define BK 64
#define KDIM 1024
#define NTI 16            // K-tiles (K=1024 always in this problem)

template <int RESID, int OUTM>   // RESID: 0 none, 1 f32, 2 bf16 ; OUTM: 1 f32, 2 bf16
__global__ __launch_bounds__(512, 1) void gemm_bf16(
    const u16* __restrict__ A, const u16* __restrict__ W,
    const float* __restrict__ bias, const void* Rp, void* Optr,
    int M, int N, int K)
{
  __shared__ __align__(16) u16 sT[2][2][BM * BK];  // [buf][opA/B][row*64+g*8] = 128 KB

  // XCD-aware bijective swizzle (all launches have nwg % 8 == 0)
  const int nbx = gridDim.x;
  const int nwg = nbx * gridDim.y;
  const int orig = blockIdx.y * nbx + blockIdx.x;
  const int cpx = nwg >> 3;
  const int swz = ((nwg & 7) == 0) ? ((orig & 7) * cpx + (orig >> 3)) : orig;
  const int bm = swz / nbx, bn = swz % nbx;

  const int tid = threadIdx.x;
  const int wave = tid >> 6;
  const int lane = tid & 63;
  const int wm = wave >> 2;       // 0..1 -> 128 rows
  const int wn = wave & 3;        // 0..3 -> 64 cols

  const int a_row0 = bm * BM;
  const int w_row0 = bn * BN;

  // staging coords: 512 threads; thread covers row s_r0 (+64 for 2nd load),
  // granule s_lg (16B). Dest LDS row-swizzled: phys_g = s_lg ^ (row&7).
  const int s_r0 = tid >> 3;      // 0..63
  const int s_lg = tid & 7;       // 0..7
  const int s_swz = (s_lg ^ (s_r0 & 7)) * 8;   // (64 rows preserve row&7)

  u16x8 sreg[4][2];               // 4 in-flight halves x 2 loads (static idx)

  // q -> (op, half): 0:A-h0 1:A-h1 2:B-h0 3:B-h1
  auto issue_half = [&](int q, int T) {
    const u16* base = (q < 2) ? A : W;
    const int r0 = (q < 2) ? a_row0 : w_row0;
    const int h = q & 1;
    const u16* p0 = base + (size_t)(r0 + h * 128 + s_r0) * K + T * 64 + s_lg * 8;
    sreg[q][0] = *(const u16x8*)p0;
    sreg[q][1] = *(const u16x8*)(p0 + (size_t)64 * K);
  };
  auto write_half = [&](int q, int T) {
    const int h = q & 1;
    u16* d = &sT[T & 1][q >> 1][(h * 128 + s_r0) * 64 + s_swz];
    *(u16x8*)d = sreg[q][0];
    *(u16x8*)(d + 64 * 64) = sreg[q][1];
  };

  f32x4 acc[8][4] = {};
  bf16x8 af[2][4];                // held across 2 phases (snake order)
  bf16x8 bfr[2][2];
  const int fr = lane & 15;
  const int l4 = lane >> 4;

  auto load_af = [&](int mh, int rb) {
#pragma unroll
    for (int ks = 0; ks < 2; ++ks)
#pragma unroll
      for (int mm = 0; mm < 4; ++mm) {
        const int row = wm * 128 + (mh * 4 + mm) * 16 + fr;
        af[ks][mm] = *(const bf16x8*)&sT[rb][0][row * 64 + (((ks * 4 + l4) ^ (row & 7)) * 8)];
      }
  };
  auto load_bf = [&](int nh, int rb) {
#pragma unroll
    for (int ks = 0; ks < 2; ++ks)
#pragma unroll
      for (int nn = 0; nn < 2; ++nn) {
        const int row = wn * 64 + (nh * 2 + nn) * 16 + fr;
        bfr[ks][nn] = *(const bf16x8*)&sT[rb][1][row * 64 + (((ks * 4 + l4) ^ (row & 7)) * 8)];
      }
  };

  // ---- prologue: tile0 -> LDS buf0; tile1 left in sreg; publish.
#pragma unroll
  for (int q = 0; q < 4; ++q) issue_half(q, 0);
#pragma unroll
  for (int q = 0; q < 4; ++q) write_half(q, 0);
#pragma unroll
  for (int q = 0; q < 4; ++q) issue_half(q, 1);
  asm volatile("s_waitcnt lgkmcnt(0)" ::: "memory");
  __builtin_amdgcn_s_barrier();
  __builtin_amdgcn_sched_barrier(0);

  // ---- main loop: iter i computes tiles 2i (phases 0-3, buf0) and 2i+1
  //      (phases 4-7, buf1); stages tiles 2i+2, 2i+3 with 4-phase aging.
  for (int i = 0; i < NTI / 2; ++i) {
#pragma unroll
    for (int p = 0; p < 8; ++p) {
      const int q = p & 3;
      const int wp = (p < 4) ? (2 * i + 1) : (2 * i + 2);   // half landing now
      const int tp = (p < 4) ? (2 * i + 2) : (2 * i + 3);   // half to issue
      if (wp < NTI) write_half(q, wp);
      if (tp < NTI) issue_half(q, tp);

      const int rb = (p < 4) ? 0 : 1;
      const int mh = q >> 1;                 // snake: (0,0)(0,1)(1,1)(1,0)
      const int nh = ((q + 1) >> 1) & 1;
      if (q == 0 || q == 2) load_af(mh, rb);
      if (q != 2) load_bf(nh, rb);

      __builtin_amdgcn_s_setprio(1);
#pragma unroll
      for (int mm = 0; mm < 4; ++mm)
#pragma unroll
        for (int nn = 0; nn < 2; ++nn)
#pragma unroll
          for (int ks = 0; ks < 2; ++ks)
            acc[mh * 4 + mm][nh * 2 + nn] = __builtin_amdgcn_mfma_f32_16x16x32_bf16(
                af[ks][mm], bfr[ks][nn], acc[mh * 4 + mm][nh * 2 + nn], 0, 0, 0);
      __builtin_amdgcn_s_setprio(0);

      asm volatile("s_waitcnt lgkmcnt(0)" ::: "memory");
      __builtin_amdgcn_s_barrier();
      __builtin_amdgcn_sched_barrier(0);
    }
  }

  // ---- epilogue: C/D layout col = lane&15, row = (lane>>4)*4 + reg [m89]
  const float* Rf = (const float*)Rp;
  const u16*   Rb = (const u16*)Rp;
  const int q4 = l4 * 4;
#pragma unroll
  for (int m = 0; m < 8; ++m) {
#pragma unroll
    for (int j = 0; j < 4; ++j) {
      const size_t rowoff = (size_t)(a_row0 + wm * 128 + m * 16 + q4 + j) * (size_t)N;
#pragma unroll
      for (int n = 0; n < 4; ++n) {
        const int gc = w_row0 + wn * 64 + n * 16 + fr;
        float v = acc[m][n][j];
        if (bias) v += bias[gc];
        if (RESID == 1) v += Rf[rowoff + gc];
        if (RESID == 2) v += bf2f(Rb[rowoff + gc]);
        if (OUTM == 1) ((float*)Optr)[rowoff + gc] = v;
        else           ((u16*)Optr)[rowoff + gc] = f2bf(v);
      }
    }
  }
}

// ---------------- LayerNorm: bf16 in, optional f32 out + bf16 side-copy -----
template <int OUTF32, int OUTBF16>
__global__ __launch_bounds__(256) void ln_kernel(
    const u16* Y, const float* __restrict__ g, const float* __restrict__ bta,
    float* Of32, u16* Obf)
{
  const int wave = threadIdx.x >> 6, lane = threadIdx.x & 63;
  const size_t row = (size_t)blockIdx.x * 4 + wave;
  const u16* y = Y + row * D_DIM + lane * 16;
  u16x8 v0 = *(const u16x8*)y;
  u16x8 v1 = *(const u16x8*)(y + 8);
  float x[16];
#pragma unroll
  for (int i = 0; i < 8; ++i) { x[i] = bf2f(v0[i]); x[8 + i] = bf2f(v1[i]); }
  float s = 0.f, ss = 0.f;
#pragma unroll
  for (int i = 0; i < 16; ++i) { s += x[i]; ss += x[i] * x[i]; }
#pragma unroll
  for (int off = 32; off > 0; off >>= 1) {
    s += __shfl_xor(s, off, 64);
    ss += __shfl_xor(ss, off, 64);
  }
  const float mean = s * (1.f / 1024.f);
  const float var = ss * (1.f / 1024.f) - mean * mean;
  const float rstd = rsqrtf(var + 1e-5f);
  const int c0 = lane * 16;
  float o[16];
#pragma unroll
  for (int i = 0; i < 16; ++i)
    o[i] = (x[i] - mean) * rstd * g[c0 + i] + bta[c0 + i];
  if (OUTF32) {
    float* p = Of32 + row * D_DIM + c0;
#pragma unroll
    for (int i = 0; i < 4; ++i) {
      f32x4 ov; ov[0] = o[i*4]; ov[1] = o[i*4+1]; ov[2] = o[i*4+2]; ov[3] = o[i*4+3];
      *(f32x4*)(p + i * 4) = ov;
    }
  }
  if (OUTBF16) {
    u16x8 b0, b1;
#pragma unroll
    for (int i = 0; i < 8; ++i) { b0[i] = f2bf(o[i]); b1[i] = f2bf(o[8 + i]); }
    u16* p = Obf + row * D_DIM + c0;
    *(u16x8*)p = b0;
    *(u16x8*)(p + 8) = b1;
  }
}

// ---------------- f32 -> bf16 conversion (grid-stride, 8/thread) -----------
__global__ __launch_bounds__(256) void cvt_kernel(const float* __restrict__ src,
                                                  u16* __restrict__ dst, size_t n)
{
  const size_t stride = (size_t)gridDim.x * 256 * 8;
  for (size_t i = ((size_t)blockIdx.x * 256 + threadIdx.x) * 8; i < n; i += stride) {
    f32x4 a = *(const f32x4*)(src + i);
    f32x4 b = *(const f32x4*)(src + i + 4);
    u16x8 o;
#pragma unroll
    for (int t = 0; t < 4; ++t) { o[t] = f2bf(a[t]); o[t + 4] = f2bf(b[t]); }
    *(u16x8*)(dst + i) = o;
  }
}

struct Ptr4 { const float* s[4]; u16* d[4]; };

__global__ __launch_bounds__(256) void transpose_kernel(Ptr4 p) {
  __shared__ float tile[32][33];
  const int z = blockIdx.z;
  const float* src = p.s[z];
  u16* dst = p.d[z];
  const int tx = threadIdx.x & 31, ty = threadIdx.x >> 5;
  const int gx = blockIdx.x * 32, gy = blockIdx.y * 32;
#pragma unroll
  for (int i = 0; i < 4; ++i) {
    const int r = ty + i * 8;
    tile[r][tx] = src[(size_t)(gy + r) * D_DIM + gx + tx];
  }
  __syncthreads();
#pragma unroll
  for (int i = 0; i < 4; ++i) {
    const int r = ty + i * 8;
    dst[(size_t)(gx + r) * D_DIM + gy + tx] = f2bf(tile[tx][r]);
  }
}

struct BiasArgs { const float* wout[4]; const float* bin[4]; const float* bout[4]; };

__global__ __launch_bounds__(256) void bias_kernel(BiasArgs p, float* cb) {
  const int z = blockIdx.z;
  const int i = blockIdx.x * 256 + threadIdx.x;
  const float* wrow = p.wout[z] + (size_t)i * D_DIM;
  const float* bv = p.bin[z] + 2 * D_DIM;
  float s = 0.f;
  for (int j = 0; j < D_DIM; j += 4) {
    f32x4 w4 = *(const f32x4*)&wrow[j];
    f32x4 b4 = *(const f32x4*)&bv[j];
#pragma unroll
    for (int t = 0; t < 4; ++t) s += w4[t] * b4[t];
  }
  cb[(size_t)z * D_DIM + i] = s + p.bout[z][i];
}

extern "C" void kernel_launch(void* const* d_in, const int* in_sizes, int n_in,
                              void* d_out, int out_size, void* d_ws, size_t ws_size,
                              hipStream_t stream) {
  (void)in_sizes; (void)n_in; (void)out_size; (void)ws_size;
  const size_t BD = (size_t)B_ROWS * D_DIM;
  const size_t DD = (size_t)D_DIM * D_DIM;

  const float* feat_local = (const float*)d_in[0];
  const float* feat_tact  = (const float*)d_in[1];
  const float* feat_strat = (const float*)d_in[2];
  const float* w_in[4]  = {(const float*)d_in[3],  (const float*)d_in[7],  (const float*)d_in[11], (const float*)d_in[15]};
  const float* b_in[4]  = {(const float*)d_in[4],  (const float*)d_in[8],  (const float*)d_in[12], (const float*)d_in[16]};
  const float* w_out[4] = {(const float*)d_in[5],  (const float*)d_in[9],  (const float*)d_in[13], (const float*)d_in[17]};
  const float* b_out[4] = {(const float*)d_in[6],  (const float*)d_in[10], (const float*)d_in[14], (const float*)d_in[18]};
  const float* ln_g[3] = {(const float*)d_in[19], (const float*)d_in[21], (const float*)d_in[23]};
  const float* ln_b[3] = {(const float*)d_in[20], (const float*)d_in[22], (const float*)d_in[24]};

  u16* buf0 = (u16*)d_ws;          // bf16 stream buffers
  u16* buf1 = buf0 + BD;
  u16* wvT  = buf1 + BD;           // 4*DD
  u16* wobf = wvT + 4 * DD;        // 4*DD
  u16* Wc   = wobf + 4 * DD;       // 4*DD
  float* cb = (float*)(Wc + 4 * DD);

  float* out = (float*)d_out;
  float* o_loc = out;
  float* o_tac = out + BD;
  float* o_str = out + 2 * BD;

  // 0. conversions: local -> bf16 (buf0), w_out -> bf16
  hipLaunchKernelGGL(cvt_kernel, dim3(2048), dim3(256), 0, stream, feat_local, buf0, BD);
  for (int z = 0; z < 4; ++z)
    hipLaunchKernelGGL(cvt_kernel, dim3(256), dim3(256), 0, stream, w_out[z], wobf + z * DD, DD);

  // 1. wvT_z = (w_in_z[2D:,:])^T as bf16
  Ptr4 tp;
  for (int z = 0; z < 4; ++z) { tp.s[z] = w_in[z] + 2 * DD; tp.d[z] = wvT + z * DD; }
  hipLaunchKernelGGL(transpose_kernel, dim3(32, 32, 4), dim3(256), 0, stream, tp);

  // 2. combined bias c = w_out*bv + b_out (f32)
  BiasArgs ba;
  for (int z = 0; z < 4; ++z) { ba.wout[z] = w_out[z]; ba.bin[z] = b_in[z]; ba.bout[z] = b_out[z]; }
  hipLaunchKernelGGL(bias_kernel, dim3(4, 1, 4), dim3(256), 0, stream, ba, cb);

  // 3. Wc_z = w_out_z(bf16) @ wvT_z(bf16)^T -> bf16   (grid 4x4 = 16 blocks)
  for (int z = 0; z < 4; ++z)
    hipLaunchKernelGGL((gemm_bf16<0, 2>), dim3(4, 4), dim3(512), 0, stream,
                       wobf + z * DD, wvT + z * DD, (const float*)nullptr,
                       (const void*)nullptr, (void*)(Wc + z * DD), 1024, 1024, 1024);

  // 4. S1: y1 = lbf @ Wc0^T + c0 + tact(f32) -> buf1 bf16; tacA = LN1(y1) in-place
  hipLaunchKernelGGL((gemm_bf16<1, 2>), dim3(4, 256), dim3(512), 0, stream,
                     buf0, Wc + 0 * DD, cb + 0, (const void*)feat_tact, (void*)buf1,
                     B_ROWS, D_DIM, D_DIM);
  hipLaunchKernelGGL((ln_kernel<0, 1>), dim3(B_ROWS / 4), dim3(256), 0, stream,
                     buf1, ln_g[0], ln_b[0], (float*)nullptr, buf1);

  // 5. S2: y2 = tacA @ Wc1^T + c1 + strat(f32) -> buf0 bf16; LN2 -> strat f32 + bf16
  hipLaunchKernelGGL((gemm_bf16<1, 2>), dim3(4, 256), dim3(512), 0, stream,
                     buf1, Wc + 1 * DD, cb + 1024, (const void*)feat_strat, (void*)buf0,
                     B_ROWS, D_DIM, D_DIM);
  hipLaunchKernelGGL((ln_kernel<1, 1>), dim3(B_ROWS / 4), dim3(256), 0, stream,
                     buf0, ln_g[1], ln_b[1], o_str, buf0);

  // 6. S3: y3 = strat_bf @ Wc2^T + c2 + tacA(bf16) -> buf1 bf16; LN3 -> tac f32 + bf16
  hipLaunchKernelGGL((gemm_bf16<2, 2>), dim3(4, 256), dim3(512), 0, stream,
                     buf0, Wc + 2 * DD, cb + 2048, (const void*)buf1, (void*)buf1,
                     B_ROWS, D_DIM, D_DIM);
  hipLaunchKernelGGL((ln_kernel<1, 1>), dim3(B_ROWS / 4), dim3(256), 0, stream,
                     buf1, ln_g[2], ln_b[2], o_tac, buf1);

  // 7. S4: loc = local(f32) + tacB @ Wc3^T + c3 -> chunk0 f32 (no LN)
  hipLaunchKernelGGL((gemm_bf16<1, 1>), dim3(4, 256), dim3(512), 0, stream,
                     buf1, Wc + 3 * DD, cb + 3072, (const void*)feat_local, (void*)o_loc,
                     B_ROWS, D_DIM, D_DIM);
}

// Round 9
// 1747.577 us; speedup vs baseline: 1.3829x; 1.3829x over previous
//
#include <hip/hip_runtime.h>

#define D_DIM 1024
#define B_ROWS 65536
#define NKT 16                 // K tiles (K = 1024 everywhere)
#define TILE_U16 8192          // 128 rows x 64 cols bf16

typedef unsigned short u16;
typedef __attribute__((ext_vector_type(8))) __bf16 bf16x8;
typedef __attribute__((ext_vector_type(4))) float f32x4;
typedef __attribute__((ext_vector_type(8))) unsigned short u16x8;

typedef const __attribute__((address_space(1))) void* gas_cptr;
typedef __attribute__((address_space(3))) void* las_ptr;

__device__ __forceinline__ u16 f2bf(float f) {
  union { float fv; unsigned int i; } v; v.fv = f;
  return (u16)((v.i + 0x7FFFu + ((v.i >> 16) & 1u)) >> 16);
}
__device__ __forceinline__ float bf2f(u16 u) {
  union { unsigned int i; float f; } v; v.i = ((unsigned int)u) << 16; return v.f;
}

// Packed layout: P(t,kt,r,g) = ((t*NKT+kt)*128 + r)*64 + g*8 ; stored granule g
// holds source cols kt*64 + (g^(r&7))*8 .. +8   (XOR bank swizzle baked in).

// ---------------- GEMM: C = A_pk @ W_pk^T (+bias) (+R), all-stream version --
// 128x128 tile, BK=64, 4 waves, single-buffer 2-barrier (m97), glds staging of
// CONTIGUOUS 16 KB packed tiles, LDS-staged coalesced epilogue.
template <int RESID, int OUTM>   // RESID: 0 none, 1 f32 rowmajor, 2 bf16 packed ; OUTM: 1 f32 rowmajor, 2 bf16 packed
__global__ __launch_bounds__(256, 4) void gemm_pk(
    const u16* __restrict__ Ap, const u16* __restrict__ Wp,
    const float* __restrict__ bias, const void* Rp, void* Op)
{
  __shared__ __align__(16) u16 smem[2 * TILE_U16];   // 32 KB: sA | sB, reused as eC
  u16* sA = smem;
  u16* sB = smem + TILE_U16;

  const int bm = blockIdx.y, bn = blockIdx.x;        // no swizzle: siblings share A
  const int tid = threadIdx.x;
  const int wave = tid >> 6;
  const int lane = tid & 63;
  const int wm = wave >> 1, wn = wave & 1;
  const int fr = lane & 15;
  const int l4 = lane >> 4;

  const u16* Abase = Ap + (size_t)bm * NKT * TILE_U16;
  const u16* Wbase = Wp + (size_t)bn * NKT * TILE_U16;

  f32x4 acc[4][4] = {};

  for (int kt = 0; kt < NKT; ++kt) {
    const u16* at = Abase + kt * TILE_U16;
    const u16* wt = Wbase + kt * TILE_U16;
#pragma unroll
    for (int i = 0; i < 4; ++i) {
      __builtin_amdgcn_global_load_lds((gas_cptr)(at + (i * 256 + tid) * 8),
                                       (las_ptr)(sA + (i * 256 + tid) * 8), 16, 0, 0);
      __builtin_amdgcn_global_load_lds((gas_cptr)(wt + (i * 256 + tid) * 8),
                                       (las_ptr)(sB + (i * 256 + tid) * 8), 16, 0, 0);
    }
    __syncthreads();
#pragma unroll
    for (int ks = 0; ks < 2; ++ks) {
      bf16x8 af[4], bf[4];
#pragma unroll
      for (int m = 0; m < 4; ++m) {
        const int row = wm * 64 + m * 16 + fr;
        af[m] = *(const bf16x8*)&sA[row * 64 + (((ks * 4 + l4) ^ (row & 7)) * 8)];
      }
#pragma unroll
      for (int n = 0; n < 4; ++n) {
        const int row = wn * 64 + n * 16 + fr;
        bf[n] = *(const bf16x8*)&sB[row * 64 + (((ks * 4 + l4) ^ (row & 7)) * 8)];
      }
#pragma unroll
      for (int m = 0; m < 4; ++m)
#pragma unroll
        for (int n = 0; n < 4; ++n)
          acc[m][n] = __builtin_amdgcn_mfma_f32_16x16x32_bf16(af[m], bf[n], acc[m][n], 0, 0, 0);
    }
    __syncthreads();
  }

  // -------- LDS-staged epilogue: two half-tiles of 64 rows --------
  float* eC = (float*)smem;            // 64 x 128 f32 = 32 KB, c4-XOR anti-bank
  const float* Rf = (const float*)Rp;
  const u16*   Rb = (const u16*)Rp;
  const int q4 = l4 * 4;
#pragma unroll
  for (int H = 0; H < 2; ++H) {
    if (wm == H) {
#pragma unroll
      for (int m = 0; m < 4; ++m)
#pragma unroll
        for (int j = 0; j < 4; ++j) {
          const int r = m * 16 + q4 + j;
#pragma unroll
          for (int n = 0; n < 4; ++n) {
            const int c = wn * 64 + n * 16 + fr;
            const int c4 = c >> 2;
            eC[r * 128 + ((c4 ^ ((r >> 2) & 7)) * 4) + (c & 3)] = acc[m][n][j];
          }
        }
    }
    __syncthreads();
    // read back coalesced: 1024 items of 8 cols; 4 per thread
#pragma unroll
    for (int it = 0; it < 4; ++it) {
      const int idx = it * 256 + tid;
      const int r = idx >> 4;          // 0..63
      const int g8 = idx & 15;         // 8-col group within 128
      const int gr = bm * 128 + H * 64 + r;
      const int c4a = g8 * 2, c4b = g8 * 2 + 1;
      const int rx = (r >> 2) & 7;
      f32x4 c0 = *(const f32x4*)&eC[r * 128 + ((c4a ^ rx) * 4)];
      f32x4 c1 = *(const f32x4*)&eC[r * 128 + ((c4b ^ rx) * 4)];
      const int gc0 = bn * 128 + g8 * 8;
      if (bias) {
        f32x4 b0 = *(const f32x4*)&bias[gc0];
        f32x4 b1 = *(const f32x4*)&bias[gc0 + 4];
#pragma unroll
        for (int t = 0; t < 4; ++t) { c0[t] += b0[t]; c1[t] += b1[t]; }
      }
      if (RESID == 1) {
        const float* rp = Rf + (size_t)gr * D_DIM + gc0;
        f32x4 r0 = *(const f32x4*)rp;
        f32x4 r1 = *(const f32x4*)(rp + 4);
#pragma unroll
        for (int t = 0; t < 4; ++t) { c0[t] += r0[t]; c1[t] += r1[t]; }
      }
      if (RESID == 2) {
        const int t_r = gr >> 7, rr = gr & 127;
        const int kt = gc0 >> 6, gs = (gc0 & 63) >> 3;
        const size_t P = ((size_t)(t_r * NKT + kt) * 128 + rr) * 64 + ((gs ^ (rr & 7)) * 8);
        u16x8 rv = *(const u16x8*)&Rb[P];
#pragma unroll
        for (int t = 0; t < 4; ++t) { c0[t] += bf2f(rv[t]); c1[t] += bf2f(rv[t + 4]); }
      }
      if (OUTM == 1) {
        float* op = (float*)Op + (size_t)gr * D_DIM + gc0;
        *(f32x4*)op = c0;
        *(f32x4*)(op + 4) = c1;
      } else {
        const int t_r = gr >> 7, rr = gr & 127;
        const int kt = gc0 >> 6, gs = (gc0 & 63) >> 3;
        const size_t P = ((size_t)(t_r * NKT + kt) * 128 + rr) * 64 + ((gs ^ (rr & 7)) * 8);
        u16x8 ov;
#pragma unroll
        for (int t = 0; t < 4; ++t) { ov[t] = f2bf(c0[t]); ov[t + 4] = f2bf(c1[t]); }
        *(u16x8*)&((u16*)Op)[P] = ov;
      }
    }
    __syncthreads();
  }
}

// ---------------- LayerNorm over packed tiles (in-place bf16 + opt f32) -----
// block = tile t_r; thread: kt = tid&15, row-group = tid>>4 (8 rows each).
template <int OUTF32>
__global__ __launch_bounds__(256) void ln_tile(
    const u16* __restrict__ Yp, const float* __restrict__ g,
    const float* __restrict__ bta, float* Of32, u16* Obf)
{
  const int t_r = blockIdx.x;
  const int kt = threadIdx.x & 15;
  const int rgrp = threadIdx.x >> 4;
#pragma unroll
  for (int ri = 0; ri < 8; ++ri) {
    const int rr = rgrp * 8 + ri;
    const size_t base = ((size_t)(t_r * NKT + kt) * 128 + rr) * 64;
    u16x8 d[8];
#pragma unroll
    for (int gg = 0; gg < 8; ++gg) d[gg] = *(const u16x8*)&Yp[base + gg * 8];
    float s = 0.f, ss = 0.f;
#pragma unroll
    for (int gg = 0; gg < 8; ++gg)
#pragma unroll
      for (int e = 0; e < 8; ++e) { float x = bf2f(d[gg][e]); s += x; ss += x * x; }
#pragma unroll
    for (int off = 1; off < 16; off <<= 1) {
      s += __shfl_xor(s, off, 64);
      ss += __shfl_xor(ss, off, 64);
    }
    const float mean = s * (1.f / 1024.f);
    const float var = ss * (1.f / 1024.f) - mean * mean;
    const float rstd = rsqrtf(var + 1e-5f);
    const int rx = rr & 7;
#pragma unroll
    for (int gg = 0; gg < 8; ++gg) {
      const int c = kt * 64 + ((gg ^ rx) * 8);
      f32x4 g0 = *(const f32x4*)&g[c];
      f32x4 g1 = *(const f32x4*)&g[c + 4];
      f32x4 b0 = *(const f32x4*)&bta[c];
      f32x4 b1 = *(const f32x4*)&bta[c + 4];
      float o[8];
#pragma unroll
      for (int e = 0; e < 4; ++e) {
        o[e] = (bf2f(d[gg][e]) - mean) * rstd * g0[e] + b0[e];
        o[e + 4] = (bf2f(d[gg][e + 4]) - mean) * rstd * g1[e] + b1[e];
      }
      u16x8 ob;
#pragma unroll
      for (int e = 0; e < 8; ++e) ob[e] = f2bf(o[e]);
      *(u16x8*)&Obf[base + gg * 8] = ob;
      if (OUTF32) {
        float* p = Of32 + (size_t)(t_r * 128 + rr) * D_DIM + c;
        f32x4 w0, w1;
#pragma unroll
        for (int e = 0; e < 4; ++e) { w0[e] = o[e]; w1[e] = o[e + 4]; }
        *(f32x4*)p = w0;
        *(f32x4*)(p + 4) = w1;
      }
    }
  }
}

// ---------------- f32 row-major -> bf16 packed tiles (block = tile row) ----
__global__ __launch_bounds__(256) void pack_f32_tile(
    const float* __restrict__ src, u16* __restrict__ dst)
{
  const int t_r = blockIdx.x;
#pragma unroll 4
  for (int i = 0; i < 64; ++i) {
    const int idx = i * 256 + threadIdx.x;
    const int r = idx >> 7;            // 0..127
    const int gsf = idx & 127;         // 8-col group within full row
    const float* sp = src + (size_t)(t_r * 128 + r) * D_DIM + gsf * 8;
    f32x4 a = *(const f32x4*)sp;
    f32x4 b = *(const f32x4*)(sp + 4);
    u16x8 o;
#pragma unroll
    for (int t = 0; t < 4; ++t) { o[t] = f2bf(a[t]); o[t + 4] = f2bf(b[t]); }
    const int kt = gsf >> 3, g3 = gsf & 7;
    dst[((size_t)(t_r * NKT + kt) * 128 + r) * 64 + ((g3 ^ (r & 7)) * 8)] = o[0],
    *(u16x8*)&dst[((size_t)(t_r * NKT + kt) * 128 + r) * 64 + ((g3 ^ (r & 7)) * 8)] = o;
  }
}

struct TP4 { const float* s[4]; u16* d[4]; };

// wv (f32 row-major) -> wv^T packed bf16, batched z=0..3
__global__ __launch_bounds__(256) void transpose_pack(TP4 p) {
  __shared__ float tile[32][33];
  const int z = blockIdx.z;
  const float* src = p.s[z];
  u16* dst = p.d[z];
  const int tx = threadIdx.x & 31, ty = threadIdx.x >> 5;
  const int gx = blockIdx.x * 32, gy = blockIdx.y * 32;
#pragma unroll
  for (int i = 0; i < 4; ++i) {
    const int r = ty + i * 8;
    tile[r][tx] = src[(size_t)(gy + r) * D_DIM + gx + tx];
  }
  __syncthreads();
#pragma unroll
  for (int i = 0; i < 4; ++i) {
    const int drow = gx + ty + i * 8;
    const int dcol = gy + tx;
    const int t_n = drow >> 7, rr = drow & 127;
    const int kt = dcol >> 6, gs = (dcol >> 3) & 7, e = dcol & 7;
    dst[((size_t)(t_n * NKT + kt) * 128 + rr) * 64 + ((gs ^ (rr & 7)) * 8) + e] =
        f2bf(tile[tx][ty + i * 8]);
  }
}

struct BiasArgs { const float* wout[4]; const float* bin[4]; const float* bout[4]; };

__global__ __launch_bounds__(256) void bias_kernel(BiasArgs p, float* cb) {
  const int z = blockIdx.z;
  const int i = blockIdx.x * 256 + threadIdx.x;
  const float* wrow = p.wout[z] + (size_t)i * D_DIM;
  const float* bv = p.bin[z] + 2 * D_DIM;
  float s = 0.f;
  for (int j = 0; j < D_DIM; j += 4) {
    f32x4 w4 = *(const f32x4*)&wrow[j];
    f32x4 b4 = *(const f32x4*)&bv[j];
#pragma unroll
    for (int t = 0; t < 4; ++t) s += w4[t] * b4[t];
  }
  cb[(size_t)z * D_DIM + i] = s + p.bout[z][i];
}

extern "C" void kernel_launch(void* const* d_in, const int* in_sizes, int n_in,
                              void* d_out, int out_size, void* d_ws, size_t ws_size,
                              hipStream_t stream) {
  (void)in_sizes; (void)n_in; (void)out_size; (void)ws_size;
  const size_t BD = (size_t)B_ROWS * D_DIM;
  const size_t DD = (size_t)D_DIM * D_DIM;

  const float* feat_local = (const float*)d_in[0];
  const float* feat_tact  = (const float*)d_in[1];
  const float* feat_strat = (const float*)d_in[2];
  const float* w_in[4]  = {(const float*)d_in[3],  (const float*)d_in[7],  (const float*)d_in[11], (const float*)d_in[15]};
  const float* b_in[4]  = {(const float*)d_in[4],  (const float*)d_in[8],  (const float*)d_in[12], (const float*)d_in[16]};
  const float* w_out[4] = {(const float*)d_in[5],  (const float*)d_in[9],  (const float*)d_in[13], (const float*)d_in[17]};
  const float* b_out[4] = {(const float*)d_in[6],  (const float*)d_in[10], (const float*)d_in[14], (const float*)d_in[18]};
  const float* ln_g[3] = {(const float*)d_in[19], (const float*)d_in[21], (const float*)d_in[23]};
  const float* ln_b[3] = {(const float*)d_in[20], (const float*)d_in[22], (const float*)d_in[24]};

  u16* buf0 = (u16*)d_ws;          // packed bf16 stream buffers (128 MB each)
  u16* buf1 = buf0 + BD;
  u16* wvT_p  = buf1 + BD;         // 4*DD packed
  u16* wobf_p = wvT_p + 4 * DD;    // 4*DD packed
  u16* Wc_p   = wobf_p + 4 * DD;   // 4*DD packed
  float* cb = (float*)(Wc_p + 4 * DD);

  float* out = (float*)d_out;
  float* o_loc = out;
  float* o_tac = out + BD;
  float* o_str = out + 2 * BD;

  // 0. pack local f32 -> packed bf16 (buf0); pack w_out -> wobf_p
  hipLaunchKernelGGL(pack_f32_tile, dim3(512), dim3(256), 0, stream, feat_local, buf0);
  for (int z = 0; z < 4; ++z)
    hipLaunchKernelGGL(pack_f32_tile, dim3(8), dim3(256), 0, stream, w_out[z], wobf_p + z * DD);

  // 1. wvT packed = (w_in[2D:,:])^T
  TP4 tp;
  for (int z = 0; z < 4; ++z) { tp.s[z] = w_in[z] + 2 * DD; tp.d[z] = wvT_p + z * DD; }
  hipLaunchKernelGGL(transpose_pack, dim3(32, 32, 4), dim3(256), 0, stream, tp);

  // 2. combined bias c = w_out*bv + b_out (f32)
  BiasArgs ba;
  for (int z = 0; z < 4; ++z) { ba.wout[z] = w_out[z]; ba.bin[z] = b_in[z]; ba.bout[z] = b_out[z]; }
  hipLaunchKernelGGL(bias_kernel, dim3(4, 1, 4), dim3(256), 0, stream, ba, cb);

  // 3. Wc_z = w_out_z @ wv_z  (packed in, packed out)
  for (int z = 0; z < 4; ++z)
    hipLaunchKernelGGL((gemm_pk<0, 2>), dim3(8, 8), dim3(256), 0, stream,
                       wobf_p + z * DD, wvT_p + z * DD, (const float*)nullptr,
                       (const void*)nullptr, (void*)(Wc_p + z * DD));

  // 4. S1: y1 = local_pk @ Wc0 + c0 + tact(f32) -> buf1 packed; LN1 in-place
  hipLaunchKernelGGL((gemm_pk<1, 2>), dim3(8, 512), dim3(256), 0, stream,
                     buf0, Wc_p + 0 * DD, cb + 0, (const void*)feat_tact, (void*)buf1);
  hipLaunchKernelGGL((ln_tile<0>), dim3(512), dim3(256), 0, stream,
                     buf1, ln_g[0], ln_b[0], (float*)nullptr, buf1);

  // 5. S2: y2 = tacA @ Wc1 + c1 + strat(f32) -> buf0 packed; LN2 -> o_str f32 + in-place
  hipLaunchKernelGGL((gemm_pk<1, 2>), dim3(8, 512), dim3(256), 0, stream,
                     buf1, Wc_p + 1 * DD, cb + 1024, (const void*)feat_strat, (void*)buf0);
  hipLaunchKernelGGL((ln_tile<1>), dim3(512), dim3(256), 0, stream,
                     buf0, ln_g[1], ln_b[1], o_str, buf0);

  // 6. S3: y3 = strat_bf @ Wc2 + c2 + tacA(packed) -> buf1 packed in-place; LN3 -> o_tac + in-place
  hipLaunchKernelGGL((gemm_pk<2, 2>), dim3(8, 512), dim3(256), 0, stream,
                     buf0, Wc_p + 2 * DD, cb + 2048, (const void*)buf1, (void*)buf1);
  hipLaunchKernelGGL((ln_tile<1>), dim3(512), dim3(256), 0, stream,
                     buf1, ln_g[2], ln_b[2], o_tac, buf1);

  // 7. S4: loc = local(f32) + tacB @ Wc3 + c3 -> o_loc f32
  hipLaunchKernelGGL((gemm_pk<1, 1>), dim3(8, 512), dim3(256), 0, stream,
                     buf1, Wc_p + 3 * DD, cb + 3072, (const void*)feat_local, (void*)o_loc);
}